// Round 15
// baseline (144.600 us; speedup 1.0000x reference)
//
#include <hip/hip_runtime.h>
#include <hip/hip_fp16.h>

// PosteriorHiddenTreeMarkovModel — MI355X / gfx950
// R15 = R14 with the 5 `else { #pragma unroll` syntax errors fixed (pragma
// must start its own line; the small fill loops don't need it).
// R14 idea: node-pairing to halve A/ALA LDS traffic (measured bottleneck:
// LDS pipe ~60% of the 81us wall, VALU ~20%).
//  - A-row b128 loads depend only on (g,p): a lane processing TWO same-p
//    nodes reuses each float4 for both -> per-j 4 b128 feed 64 FMAs (2x).
//  - Up-pass: A depends on k (uniform) -> generic pairs (base+n, base+8+n).
//    Down-pass: pair gap ==0 mod 3 -> gap 24 at e=4, gap 12 at e=3; e<=2 single.
//  - Bmv as per-j scalar global loads (L1 same-line) to keep VGPR <= ~120.
// Everything else identical to R13: 432 blocks, 1 wave/subtree, per-tree
// relaxed-poll sync, fp16 bMid, cached mid b3 reads after one fence.

namespace {

constexpr int kNPT = 3280;
constexpr int kRS  = 72;   // subtree record stride: 64 beta + 8 pre-norm sums
constexpr int kAS  = 68;   // A row stride per (g,p)
constexpr unsigned kMAGIC  = 0x13579BDFu;
constexpr unsigned kMAGIC2 = 0x2468ACEFu;
__device__ __constant__ int LO[6] = {0, 1, 4, 13, 40, 121};
__device__ __constant__ int P3[5] = {1, 3, 9, 27, 81};

#define AGENT_LD(p)    __hip_atomic_load((p), __ATOMIC_RELAXED, __HIP_MEMORY_SCOPE_AGENT)
#define AGENT_ST(p, v) __hip_atomic_store((p), (v), __ATOMIC_RELAXED, __HIP_MEMORY_SCOPE_AGENT)

__device__ __forceinline__ void leaf_beta(const float* __restrict__ sPi,
                                          const float* __restrict__ pBm,
                                          int p, int xv, int g, float* b)
{
    float s = 0.f;
    #pragma unroll
    for (int c = 0; c < 8; ++c) {
        b[c] = sPi[(c * 3 + p) * 8 + g] * pBm[xv * 64 + c * 8 + g];
        s += b[c];
    }
    float ig = __builtin_amdgcn_rcpf(s);
    #pragma unroll
    for (int c = 0; c < 8; ++c) b[c] *= ig;
}

// acc[i] += (spg*bj[j]) * A[i][j] over j; A row via 2x b128 per j (mid only)
__device__ __forceinline__ void matvec_acc(const float* __restrict__ arow,
                                           const float* __restrict__ bj,
                                           float spg, float* acc)
{
    #pragma unroll
    for (int j = 0; j < 8; ++j) {
        float4 a0 = *(const float4*)(arow + j * 8);
        float4 a1 = *(const float4*)(arow + j * 8 + 4);
        float cjv = spg * bj[j];
        acc[0] = fmaf(a0.x, cjv, acc[0]); acc[1] = fmaf(a0.y, cjv, acc[1]);
        acc[2] = fmaf(a0.z, cjv, acc[2]); acc[3] = fmaf(a0.w, cjv, acc[3]);
        acc[4] = fmaf(a1.x, cjv, acc[4]); acc[5] = fmaf(a1.y, cjv, acc[5]);
        acc[6] = fmaf(a1.z, cjv, acc[6]); acc[7] = fmaf(a1.w, cjv, acc[7]);
    }
}

__global__ __launch_bounds__(256, 2)
void fused(const float* __restrict__ lamA, const float* __restrict__ lamB,
           const float* __restrict__ lamPi, const float* __restrict__ lamSP,
           const int* __restrict__ x, float* __restrict__ out,
           unsigned* __restrict__ sy, float* __restrict__ bmG,
           float* __restrict__ b3, float* __restrict__ e3)
{
    const int tid = threadIdx.x, w = tid >> 6, lane = tid & 63;
    const int n = lane >> 3, g = lane & 7;
    __shared__ __align__(16) float sAg[24 * kAS];   // A    [g][p][j][i]
    __shared__ __align__(16) float sLAg[24 * kAS];  // AlogA same layout
    __shared__ float sPi[192], sLPi[192], sSP[24], sLSP[24];
    __shared__ float bW[4][40 * kRS];               // per-subtree records
    __shared__ __half bMidH[13 * 64];               // mid beta, fp16
    __shared__ float sMs[13 * 8];                   // mid pre-norm sums
    __shared__ unsigned char xW[4][124];
    unsigned* trCnt = sy + 32;
    unsigned* trFlg = sy + 2080;

    // ---- init gate ----
    if (tid == 0) {
        if (blockIdx.x == 0) {
            for (int i = 0; i < 64; ++i) AGENT_ST(&trCnt[i * 32], 0u);
            __builtin_amdgcn_s_waitcnt(0);
            AGENT_ST(&sy[0], kMAGIC);
        }
        unsigned long sp = 0;
        while (AGENT_LD(&sy[0]) != kMAGIC) {
            if (++sp > (1UL << 24)) break;
            __builtin_amdgcn_s_sleep(2);
        }
    }
    __syncthreads();

    // ================= phase 0: parameters =================
    if (blockIdx.x == 0) {   // Bm softmax -> bmG (transposed [m][c][g]) + flag
        float* rr = &bW[0][0];
        int row = tid >> 2, part = tid & 3;
        int c = row >> 3, gg = row & 7, m0 = part * 32;
        float mx = -1e30f;
        for (int mm = 0; mm < 32; ++mm)
            mx = fmaxf(mx, lamB[(c * 128 + m0 + mm) * 8 + gg]);
        rr[tid] = mx;
        __syncthreads();
        float m4 = fmaxf(fmaxf(rr[row * 4], rr[row * 4 + 1]),
                         fmaxf(rr[row * 4 + 2], rr[row * 4 + 3]));
        float s = 0.f;
        for (int mm = 0; mm < 32; ++mm)
            s += expf(lamB[(c * 128 + m0 + mm) * 8 + gg] - m4);
        rr[256 + tid] = s;
        __syncthreads();
        float stot = rr[256 + row * 4] + rr[256 + row * 4 + 1]
                   + rr[256 + row * 4 + 2] + rr[256 + row * 4 + 3];
        float inv = 1.f / stot;
        for (int mm = 0; mm < 32; ++mm)
            AGENT_ST(&bmG[(m0 + mm) * 64 + c * 8 + gg],
                     expf(lamB[(c * 128 + m0 + mm) * 8 + gg] - m4) * inv);
        __syncthreads();
        if (tid == 0) AGENT_ST(&sy[4], kMAGIC2);
    }
    for (int col = tid; col < 192; col += 256) {   // A softmax over i -> g-major
        int j = col / 24; int rem = col - j * 24; int p = rem >> 3; int gg = rem & 7;
        float v[8]; float mx = -1e30f;
        #pragma unroll
        for (int i = 0; i < 8; ++i) {
            v[i] = lamA[((i * 8 + j) * 3 + p) * 8 + gg];
            mx = fmaxf(mx, v[i]);
        }
        float s = 0.f;
        #pragma unroll
        for (int i = 0; i < 8; ++i) { v[i] = expf(v[i] - mx); s += v[i]; }
        float inv = 1.f / s;
        int base = (gg * 3 + p) * kAS + j * 8;
        #pragma unroll
        for (int i = 0; i < 8; ++i) {
            float sm = v[i] * inv;
            sAg[base + i]  = sm;
            sLAg[base + i] = sm * logf(sm);
        }
    }
    for (int col = tid; col < 24; col += 256) {    // Pi softmax over c
        int p = col >> 3; int gg = col & 7;
        float v[8]; float mx = -1e30f;
        #pragma unroll
        for (int c = 0; c < 8; ++c) {
            v[c] = lamPi[(c * 3 + p) * 8 + gg];
            mx = fmaxf(mx, v[c]);
        }
        float s = 0.f;
        #pragma unroll
        for (int c = 0; c < 8; ++c) { v[c] = expf(v[c] - mx); s += v[c]; }
        float inv = 1.f / s;
        #pragma unroll
        for (int c = 0; c < 8; ++c) {
            int idx = (c * 3 + p) * 8 + gg;
            float sm = v[c] * inv;
            sPi[idx]  = sm;
            sLPi[idx] = logf(sm);
        }
    }
    if (tid < 8) {                                 // SP softmax over p
        int gg = tid;
        float v0 = lamSP[gg], v1 = lamSP[8 + gg], v2 = lamSP[16 + gg];
        float mx = fmaxf(v0, fmaxf(v1, v2));
        float e0 = expf(v0 - mx), e1 = expf(v1 - mx), e2 = expf(v2 - mx);
        float inv = 1.f / (e0 + e1 + e2);
        sSP[gg] = e0 * inv; sSP[8 + gg] = e1 * inv; sSP[16 + gg] = e2 * inv;
        sLSP[gg] = logf(e0 * inv); sLSP[8 + gg] = logf(e1 * inv); sLSP[16 + gg] = logf(e2 * inv);
    }
    if (tid == 0) {        // Bm gate: one fence per block per launch
        unsigned long sp = 0;
        while (AGENT_LD(&sy[4]) != kMAGIC2) {
            if (++sp > (1UL << 24)) break;
            __builtin_amdgcn_s_sleep(2);
        }
        __threadfence();
    }
    __syncthreads();

    const float* pBm = bmG;
    const int id = blockIdx.x * 4 + w, t = id / 27, q = id % 27, xb = t * kNPT;
    float* bw = &bW[w][0];
    unsigned char* xw = &xW[w][0];

    // ================= phase 1: subtree up-pass (paired) =================
    for (int u = lane; u < 121; u += 64) {
        int gx;
        if (u == 0)       gx = 13 + q;
        else if (u < 4)   gx = 40  + q * 3  + (u - 1);
        else if (u < 13)  gx = 121 + q * 9  + (u - 4);
        else if (u < 40)  gx = 364 + q * 27 + (u - 13);
        else              gx = 1093 + q * 81 + (u - 40);
        xw[u] = (unsigned char)x[xb + gx];
    }
    __builtin_amdgcn_wave_barrier();

    for (int e = 3; e >= 0; --e) {
        int cnt = P3[e];
        for (int base = 0; base < cnt; base += 16) {
            int n1 = base + n;
            int n2 = base + 8 + n;
            bool v1 = n1 < cnt;
            bool v2 = n2 < cnt;
            if (v1) {
                float acc1[8], acc2[8];
                #pragma unroll
                for (int i = 0; i < 8; ++i) { acc1[i] = 0.f; acc2[i] = 0.f; }
                #pragma unroll
                for (int k = 0; k < 3; ++k) {
                    float bj1[8], bj2[8];
                    if (e == 3) {
                        leaf_beta(sPi, pBm, k, xw[40 + 3 * n1 + k], g, bj1);
                        if (v2) {
                            leaf_beta(sPi, pBm, k, xw[40 + 3 * n2 + k], g, bj2);
                        } else {
                            for (int j = 0; j < 8; ++j) bj2[j] = 0.f;
                        }
                    } else {
                        int co1 = (LO[e + 1] + 3 * n1 + k) * kRS + g;
                        #pragma unroll
                        for (int j = 0; j < 8; ++j) bj1[j] = bw[co1 + j * 8];
                        if (v2) {
                            int co2 = (LO[e + 1] + 3 * n2 + k) * kRS + g;
                            #pragma unroll
                            for (int j = 0; j < 8; ++j) bj2[j] = bw[co2 + j * 8];
                        } else {
                            for (int j = 0; j < 8; ++j) bj2[j] = 0.f;
                        }
                    }
                    const float* arow = &sAg[(g * 3 + k) * kAS];
                    float spg = sSP[k * 8 + g];
                    #pragma unroll
                    for (int j = 0; j < 8; ++j) {
                        float4 a0 = *(const float4*)(arow + j * 8);
                        float4 a1 = *(const float4*)(arow + j * 8 + 4);
                        float c1v = spg * bj1[j], c2v = spg * bj2[j];
                        acc1[0] = fmaf(a0.x, c1v, acc1[0]); acc1[1] = fmaf(a0.y, c1v, acc1[1]);
                        acc1[2] = fmaf(a0.z, c1v, acc1[2]); acc1[3] = fmaf(a0.w, c1v, acc1[3]);
                        acc1[4] = fmaf(a1.x, c1v, acc1[4]); acc1[5] = fmaf(a1.y, c1v, acc1[5]);
                        acc1[6] = fmaf(a1.z, c1v, acc1[6]); acc1[7] = fmaf(a1.w, c1v, acc1[7]);
                        acc2[0] = fmaf(a0.x, c2v, acc2[0]); acc2[1] = fmaf(a0.y, c2v, acc2[1]);
                        acc2[2] = fmaf(a0.z, c2v, acc2[2]); acc2[3] = fmaf(a0.w, c2v, acc2[3]);
                        acc2[4] = fmaf(a1.x, c2v, acc2[4]); acc2[5] = fmaf(a1.y, c2v, acc2[5]);
                        acc2[6] = fmaf(a1.z, c2v, acc2[6]); acc2[7] = fmaf(a1.w, c2v, acc2[7]);
                    }
                }
                if (e == 0) {
                    #pragma unroll
                    for (int i = 0; i < 8; ++i) bw[i * 8 + g] = acc1[i];  // raw tb root
                    int xv = xw[0];
                    float s = 0.f;
                    #pragma unroll
                    for (int i = 0; i < 8; ++i) { acc1[i] *= pBm[xv * 64 + i * 8 + g]; s += acc1[i]; }
                    float ig = __builtin_amdgcn_rcpf(s);
                    #pragma unroll
                    for (int i = 0; i < 8; ++i)
                        AGENT_ST(&b3[id * 64 + i * 8 + g], acc1[i] * ig);
                } else {
                    int slot = LO[e] + n1;
                    int xv = xw[slot];
                    float s = 0.f;
                    #pragma unroll
                    for (int i = 0; i < 8; ++i) { acc1[i] *= pBm[xv * 64 + i * 8 + g]; s += acc1[i]; }
                    float ig = __builtin_amdgcn_rcpf(s);
                    int bo = slot * kRS + g;
                    #pragma unroll
                    for (int i = 0; i < 8; ++i) bw[bo + i * 8] = acc1[i] * ig;
                    bw[slot * kRS + 64 + g] = s;
                    if (v2) {
                        int slot2 = LO[e] + n2;
                        int xv2 = xw[slot2];
                        float s2 = 0.f;
                        #pragma unroll
                        for (int i = 0; i < 8; ++i) { acc2[i] *= pBm[xv2 * 64 + i * 8 + g]; s2 += acc2[i]; }
                        float ig2 = __builtin_amdgcn_rcpf(s2);
                        int bo2 = slot2 * kRS + g;
                        #pragma unroll
                        for (int i = 0; i < 8; ++i) bw[bo2 + i * 8] = acc2[i] * ig2;
                        bw[slot2 * kRS + 64 + g] = s2;
                    }
                }
            }
        }
        __builtin_amdgcn_wave_barrier();
    }
    __builtin_amdgcn_s_waitcnt(0);
    if (lane == 0)
        __hip_atomic_fetch_add(&trCnt[t * 32], 1u, __ATOMIC_RELAXED,
                               __HIP_MEMORY_SCOPE_AGENT);

    // ================= phase 2: mid (levels 0-3), q==0 wave per tree =========
    if (q == 0) {
        unsigned long sp = 0;
        while (AGENT_LD(&trCnt[t * 32]) < 27u) {
            if (++sp > (1UL << 22)) break;
            __builtin_amdgcn_s_sleep(1);
        }
        __threadfence();   // one invalidate; b3 then read via cached loads
        float ellm = 0.f;
        for (int f = 2; f >= 0; --f) {
            int cnt = (f == 2) ? 9 : (f == 1 ? 3 : 1);
            int pl0 = (f == 2) ? 4 : (f == 1 ? 1 : 0);
            int cl0 = (f == 1) ? 4 : 1;
            for (int base = 0; base < cnt; base += 8) {
                int pi = base + n;
                if (pi < cnt) {
                    float acc[8];
                    #pragma unroll
                    for (int i = 0; i < 8; ++i) acc[i] = 0.f;
                    #pragma unroll
                    for (int k = 0; k < 3; ++k) {
                        float bj[8];
                        if (f == 2) {
                            const float* src = b3 + (t * 27 + 3 * pi + k) * 64 + g;
                            #pragma unroll
                            for (int j = 0; j < 8; ++j) bj[j] = src[j * 8];
                        } else {
                            int co = (cl0 + 3 * pi + k) * 64 + g;
                            #pragma unroll
                            for (int j = 0; j < 8; ++j)
                                bj[j] = __half2float(bMidH[co + j * 8]);
                        }
                        matvec_acc(&sAg[(g * 3 + k) * kAS], bj, sSP[k * 8 + g], acc);
                    }
                    int slot = pl0 + pi;
                    int xv = x[xb + slot];
                    float s = 0.f;
                    #pragma unroll
                    for (int i = 0; i < 8; ++i) { acc[i] *= pBm[xv * 64 + i * 8 + g]; s += acc[i]; }
                    float ig = __builtin_amdgcn_rcpf(s);
                    int bo = slot * 64 + g;
                    #pragma unroll
                    for (int i = 0; i < 8; ++i)
                        bMidH[bo + i * 8] = __float2half(acc[i] * ig);
                    sMs[slot * 8 + g] = s;
                }
            }
            __builtin_amdgcn_wave_barrier();
        }
        if (n == 0) {     // root: ell Bm term; slot0 := r = Bm/s
            int xv = x[xb];
            float invs = __builtin_amdgcn_rcpf(sMs[g]);
            #pragma unroll
            for (int c = 0; c < 8; ++c)
                ellm += __half2float(bMidH[c * 8 + g]) * pBm[xv * 64 + c * 8 + g];
            #pragma unroll
            for (int c = 0; c < 8; ++c)
                bMidH[c * 8 + g] = __float2half(pBm[xv * 64 + c * 8 + g] * invs);
        }
        __builtin_amdgcn_wave_barrier();
        for (int f = 1; f <= 3; ++f) {
            int cnt = (f == 1) ? 3 : (f == 2 ? 9 : 27);
            int cl0 = (f == 1) ? 1 : (f == 2 ? 4 : 13);
            int pl0 = (f == 1) ? 0 : (f == 2 ? 1 : 4);
            for (int base = 0; base < cnt; base += 8) {
                int ci = base + n;
                if (ci < cnt) {
                    int p = ci % 3;
                    int ps = (pl0 + ci / 3) * 64 + g;
                    float r[8];
                    #pragma unroll
                    for (int i = 0; i < 8; ++i) r[i] = __half2float(bMidH[ps + i * 8]);
                    float bj[8]; float sv = 0.f;
                    if (f == 3) {
                        const float* src = b3 + (t * 27 + ci) * 64 + g;
                        #pragma unroll
                        for (int j = 0; j < 8; ++j) bj[j] = src[j * 8];
                    } else {
                        int co = (cl0 + ci) * 64 + g;
                        #pragma unroll
                        for (int j = 0; j < 8; ++j) bj[j] = __half2float(bMidH[co + j * 8]);
                        sv = sMs[(cl0 + ci) * 8 + g];
                    }
                    float spg = sSP[p * 8 + g];
                    const float* arow = &sAg[(g * 3 + p) * kAS];
                    const float* lrow = &sLAg[(g * 3 + p) * kAS];
                    float esum = 0.f, lg = 0.f;
                    float ev[8];
                    #pragma unroll
                    for (int j = 0; j < 8; ++j) {
                        float4 a0 = *(const float4*)(arow + j * 8);
                        float4 a1 = *(const float4*)(arow + j * 8 + 4);
                        float4 l0 = *(const float4*)(lrow + j * 8);
                        float4 l1 = *(const float4*)(lrow + j * 8 + 4);
                        float s1 = r[0] * a0.x; s1 = fmaf(r[1], a0.y, s1);
                        s1 = fmaf(r[2], a0.z, s1); s1 = fmaf(r[3], a0.w, s1);
                        s1 = fmaf(r[4], a1.x, s1); s1 = fmaf(r[5], a1.y, s1);
                        s1 = fmaf(r[6], a1.z, s1); s1 = fmaf(r[7], a1.w, s1);
                        float s2 = r[0] * l0.x; s2 = fmaf(r[1], l0.y, s2);
                        s2 = fmaf(r[2], l0.z, s2); s2 = fmaf(r[3], l0.w, s2);
                        s2 = fmaf(r[4], l1.x, s2); s2 = fmaf(r[5], l1.y, s2);
                        s2 = fmaf(r[6], l1.z, s2); s2 = fmaf(r[7], l1.w, s2);
                        float bs = spg * bj[j];
                        ev[j] = bs * s1;
                        lg    = fmaf(bs, s2, lg);
                        esum += ev[j];
                    }
                    lg = fmaf(esum, sLSP[p * 8 + g], lg);
                    int xv = x[xb + cl0 + ci];
                    float Bmv[8];
                    #pragma unroll
                    for (int c = 0; c < 8; ++c) {
                        Bmv[c] = pBm[xv * 64 + c * 8 + g];
                        lg = fmaf(ev[c], Bmv[c], lg);
                    }
                    if (f == 3) {
                        #pragma unroll
                        for (int j = 0; j < 8; ++j)
                            AGENT_ST(&e3[(t * 27 + ci) * 64 + j * 8 + g], ev[j]);
                    } else {
                        int co = (cl0 + ci) * 64 + g;
                        #pragma unroll
                        for (int j = 0; j < 8; ++j)
                            bMidH[co + j * 8] = __float2half(
                                ev[j] * Bmv[j] * __builtin_amdgcn_rcpf(bj[j] * sv));
                    }
                    ellm += lg;
                }
            }
            __builtin_amdgcn_wave_barrier();
        }
        ellm += __shfl_xor(ellm, 8);
        ellm += __shfl_xor(ellm, 16);
        ellm += __shfl_xor(ellm, 32);
        if (n == 0) atomicAdd(&out[t * 8 + g], -ellm);
        __builtin_amdgcn_s_waitcnt(0);
        if (lane == 0) AGENT_ST(&trFlg[t * 32], kMAGIC2);
    }

    // ================= phase 3: subtree down-pass (paired at e=3,4) ==========
    {
        unsigned long sp = 0;
        while (AGENT_LD(&trFlg[t * 32]) != kMAGIC2) {
            if (++sp > (1UL << 22)) break;
            __builtin_amdgcn_s_sleep(1);
        }
    }
    bw[lane] = AGENT_LD(&e3[id * 64 + lane]) * __builtin_amdgcn_rcpf(bw[lane]);
    __builtin_amdgcn_wave_barrier();

    float ell = 0.f;
    for (int e = 1; e <= 4; ++e) {
        int cnt = P3[e], pl0 = LO[e - 1];
        if (e >= 3) {
            int G = (e == 4) ? 24 : 12;
            for (int sb = 0; sb < cnt; sb += 2 * G)
            for (int b = sb; b < sb + G && b < cnt; b += 8) {
                int c1 = b + n;
                bool v1 = (c1 < sb + G) && (c1 < cnt);
                int c2 = c1 + G;
                bool v2 = v1 && (c2 < cnt);
                if (v1) {
                    int p = c1 % 3;                 // == c2 % 3 (G % 3 == 0)
                    float spg = sSP[p * 8 + g];
                    const float* arow = &sAg[(g * 3 + p) * kAS];
                    const float* lrow = &sLAg[(g * 3 + p) * kAS];
                    float r1[8], r2[8];
                    {
                        int ps1 = (pl0 + c1 / 3) * kRS + g;
                        #pragma unroll
                        for (int i = 0; i < 8; ++i) r1[i] = bw[ps1 + i * 8];
                    }
                    if (v2) {
                        int ps2 = (pl0 + c2 / 3) * kRS + g;
                        #pragma unroll
                        for (int i = 0; i < 8; ++i) r2[i] = bw[ps2 + i * 8];
                    } else {
                        for (int i = 0; i < 8; ++i) r2[i] = 0.f;
                    }
                    float bj1[8], bj2[8];
                    int xv1, xv2 = 0, co1 = 0, co2 = 0;
                    float sv1 = 0.f, sv2 = 0.f;
                    if (e == 4) {
                        xv1 = xw[40 + c1];
                        leaf_beta(sPi, pBm, p, xv1, g, bj1);
                        if (v2) {
                            xv2 = xw[40 + c2];
                            leaf_beta(sPi, pBm, p, xv2, g, bj2);
                        } else {
                            for (int j = 0; j < 8; ++j) bj2[j] = 0.f;
                        }
                    } else {
                        int slot1 = LO[e] + c1;
                        xv1 = xw[slot1]; co1 = slot1 * kRS + g;
                        #pragma unroll
                        for (int j = 0; j < 8; ++j) bj1[j] = bw[co1 + j * 8];
                        sv1 = bw[slot1 * kRS + 64 + g];
                        if (v2) {
                            int slot2 = LO[e] + c2;
                            xv2 = xw[slot2]; co2 = slot2 * kRS + g;
                            #pragma unroll
                            for (int j = 0; j < 8; ++j) bj2[j] = bw[co2 + j * 8];
                            sv2 = bw[slot2 * kRS + 64 + g];
                        } else {
                            for (int j = 0; j < 8; ++j) bj2[j] = 0.f;
                        }
                    }
                    float esum1 = 0.f, esum2 = 0.f, lg1 = 0.f, lg2 = 0.f;
                    #pragma unroll
                    for (int j = 0; j < 8; ++j) {
                        float4 a0 = *(const float4*)(arow + j * 8);
                        float4 a1 = *(const float4*)(arow + j * 8 + 4);
                        float4 l0 = *(const float4*)(lrow + j * 8);
                        float4 l1 = *(const float4*)(lrow + j * 8 + 4);
                        float s1a = r1[0] * a0.x; s1a = fmaf(r1[1], a0.y, s1a);
                        s1a = fmaf(r1[2], a0.z, s1a); s1a = fmaf(r1[3], a0.w, s1a);
                        s1a = fmaf(r1[4], a1.x, s1a); s1a = fmaf(r1[5], a1.y, s1a);
                        s1a = fmaf(r1[6], a1.z, s1a); s1a = fmaf(r1[7], a1.w, s1a);
                        float s1l = r1[0] * l0.x; s1l = fmaf(r1[1], l0.y, s1l);
                        s1l = fmaf(r1[2], l0.z, s1l); s1l = fmaf(r1[3], l0.w, s1l);
                        s1l = fmaf(r1[4], l1.x, s1l); s1l = fmaf(r1[5], l1.y, s1l);
                        s1l = fmaf(r1[6], l1.z, s1l); s1l = fmaf(r1[7], l1.w, s1l);
                        float s2a = r2[0] * a0.x; s2a = fmaf(r2[1], a0.y, s2a);
                        s2a = fmaf(r2[2], a0.z, s2a); s2a = fmaf(r2[3], a0.w, s2a);
                        s2a = fmaf(r2[4], a1.x, s2a); s2a = fmaf(r2[5], a1.y, s2a);
                        s2a = fmaf(r2[6], a1.z, s2a); s2a = fmaf(r2[7], a1.w, s2a);
                        float s2l = r2[0] * l0.x; s2l = fmaf(r2[1], l0.y, s2l);
                        s2l = fmaf(r2[2], l0.z, s2l); s2l = fmaf(r2[3], l0.w, s2l);
                        s2l = fmaf(r2[4], l1.x, s2l); s2l = fmaf(r2[5], l1.y, s2l);
                        s2l = fmaf(r2[6], l1.z, s2l); s2l = fmaf(r2[7], l1.w, s2l);
                        float bs1 = spg * bj1[j], bs2 = spg * bj2[j];
                        float ev1 = bs1 * s1a,  ev2 = bs2 * s2a;
                        lg1 = fmaf(bs1, s1l, lg1);
                        lg2 = fmaf(bs2, s2l, lg2);
                        esum1 += ev1; esum2 += ev2;
                        float Bm1 = pBm[xv1 * 64 + j * 8 + g];
                        float Bm2 = v2 ? pBm[xv2 * 64 + j * 8 + g] : 0.f;
                        if (e == 4) {
                            float lp = sLPi[(j * 3 + p) * 8 + g];
                            lg1 = fmaf(ev1, Bm1 + lp, lg1);
                            lg2 = fmaf(ev2, Bm2 + lp, lg2);
                        } else {
                            lg1 = fmaf(ev1, Bm1, lg1);
                            lg2 = fmaf(ev2, Bm2, lg2);
                            bw[co1 + j * 8] = ev1 * Bm1
                                * __builtin_amdgcn_rcpf(bj1[j] * sv1);
                            if (v2) bw[co2 + j * 8] = ev2 * Bm2
                                * __builtin_amdgcn_rcpf(bj2[j] * sv2);
                        }
                    }
                    lg1 = fmaf(esum1, sLSP[p * 8 + g], lg1);
                    ell += lg1;
                    if (v2) {
                        lg2 = fmaf(esum2, sLSP[p * 8 + g], lg2);
                        ell += lg2;
                    }
                }
            }
        } else {
            for (int base = 0; base < cnt; base += 8) {
                int ci = base + n;
                if (ci < cnt) {
                    int p = ci % 3;
                    int ps = (pl0 + ci / 3) * kRS + g;
                    float r[8];
                    #pragma unroll
                    for (int i = 0; i < 8; ++i) r[i] = bw[ps + i * 8];
                    int slot = LO[e] + ci;
                    int xv = xw[slot];
                    int co = slot * kRS + g;
                    float bj[8];
                    #pragma unroll
                    for (int j = 0; j < 8; ++j) bj[j] = bw[co + j * 8];
                    float sv = bw[slot * kRS + 64 + g];
                    float spg = sSP[p * 8 + g];
                    const float* arow = &sAg[(g * 3 + p) * kAS];
                    const float* lrow = &sLAg[(g * 3 + p) * kAS];
                    float esum = 0.f, lg = 0.f;
                    #pragma unroll
                    for (int j = 0; j < 8; ++j) {
                        float4 a0 = *(const float4*)(arow + j * 8);
                        float4 a1 = *(const float4*)(arow + j * 8 + 4);
                        float4 l0 = *(const float4*)(lrow + j * 8);
                        float4 l1 = *(const float4*)(lrow + j * 8 + 4);
                        float s1 = r[0] * a0.x; s1 = fmaf(r[1], a0.y, s1);
                        s1 = fmaf(r[2], a0.z, s1); s1 = fmaf(r[3], a0.w, s1);
                        s1 = fmaf(r[4], a1.x, s1); s1 = fmaf(r[5], a1.y, s1);
                        s1 = fmaf(r[6], a1.z, s1); s1 = fmaf(r[7], a1.w, s1);
                        float s2 = r[0] * l0.x; s2 = fmaf(r[1], l0.y, s2);
                        s2 = fmaf(r[2], l0.z, s2); s2 = fmaf(r[3], l0.w, s2);
                        s2 = fmaf(r[4], l1.x, s2); s2 = fmaf(r[5], l1.y, s2);
                        s2 = fmaf(r[6], l1.z, s2); s2 = fmaf(r[7], l1.w, s2);
                        float bs = spg * bj[j];
                        float ev = bs * s1;
                        lg = fmaf(bs, s2, lg);
                        esum += ev;
                        float Bm1 = pBm[xv * 64 + j * 8 + g];
                        lg = fmaf(ev, Bm1, lg);
                        bw[co + j * 8] = ev * Bm1
                            * __builtin_amdgcn_rcpf(bj[j] * sv);
                    }
                    lg = fmaf(esum, sLSP[p * 8 + g], lg);
                    ell += lg;
                }
            }
        }
        __builtin_amdgcn_wave_barrier();
    }

    ell += __shfl_xor(ell, 8);
    ell += __shfl_xor(ell, 16);
    ell += __shfl_xor(ell, 32);
    if (n == 0) atomicAdd(&out[t * 8 + g], -ell);
}

} // namespace

extern "C" void kernel_launch(void* const* d_in, const int* in_sizes, int n_in,
                              void* d_out, int out_size, void* d_ws, size_t ws_size,
                              hipStream_t stream) {
    const float* lamA  = (const float*)d_in[0];
    const float* lamB  = (const float*)d_in[1];
    const float* lamPi = (const float*)d_in[2];
    const float* lamSP = (const float*)d_in[3];
    const int*   x     = (const int*)d_in[4];
    float* out = (float*)d_out;
    unsigned* sy  = (unsigned*)d_ws;        // sync area (32 KB)
    float* bmG = (float*)d_ws + 8192;       // 8192 floats
    float* b3  = bmG + 8192;                // 1728*64
    float* e3  = b3 + 1728 * 64;            // 1728*64

    fused<<<dim3(432), dim3(256), 0, stream>>>(
        lamA, lamB, lamPi, lamSP, x, out, sy, bmG, b3, e3);
}

// Round 16
// 143.107 us; speedup vs baseline: 1.0104x; 1.0104x over previous
//
#include <hip/hip_runtime.h>
#include <hip/hip_fp16.h>

// PosteriorHiddenTreeMarkovModel — MI355X / gfx950
// R16 = R13 + p-class down-pass ordering (NO pairing — R15's pairing hit the
// 128-VGPR cap and spilled ~3MB to scratch, canceling its LDS win).
// Down-pass e>=3 iterates one p-class at a time (ci = p0 + 3*idx, p
// wave-uniform): A/ALA b128 row base (g*3+p)*68 becomes p-uniform; quad-bank
// groups 3g mod 8 are all-distinct -> conflict-free broadcast reads, same as
// the (measured conflict-free) up-pass. bw record accesses stay <=2-way
// (stride 216 floats -> 24n mod 32). Registers identical to R13 (VGPR ~96).
// Everything else identical to R13: 432 blocks, 1 wave/subtree, per-tree
// relaxed-poll sync, fp16 bMid, cached mid b3 reads after one fence.

namespace {

constexpr int kNPT = 3280;
constexpr int kRS  = 72;   // subtree record stride: 64 beta + 8 pre-norm sums
constexpr int kAS  = 68;   // A row stride per (g,p)
constexpr unsigned kMAGIC  = 0x13579BDFu;
constexpr unsigned kMAGIC2 = 0x2468ACEFu;
__device__ __constant__ int LO[6] = {0, 1, 4, 13, 40, 121};
__device__ __constant__ int P3[5] = {1, 3, 9, 27, 81};

#define AGENT_LD(p)    __hip_atomic_load((p), __ATOMIC_RELAXED, __HIP_MEMORY_SCOPE_AGENT)
#define AGENT_ST(p, v) __hip_atomic_store((p), (v), __ATOMIC_RELAXED, __HIP_MEMORY_SCOPE_AGENT)

__device__ __forceinline__ void leaf_beta(const float* __restrict__ sPi,
                                          const float* __restrict__ pBm,
                                          int p, int xv, int g, float* b)
{
    float s = 0.f;
    #pragma unroll
    for (int c = 0; c < 8; ++c) {
        b[c] = sPi[(c * 3 + p) * 8 + g] * pBm[xv * 64 + c * 8 + g];
        s += b[c];
    }
    float ig = __builtin_amdgcn_rcpf(s);
    #pragma unroll
    for (int c = 0; c < 8; ++c) b[c] *= ig;
}

// acc[i] += (spg*bj[j]) * A[i][j] over j; A row via 2x b128 per j
__device__ __forceinline__ void matvec_acc(const float* __restrict__ arow,
                                           const float* __restrict__ bj,
                                           float spg, float* acc)
{
    #pragma unroll
    for (int j = 0; j < 8; ++j) {
        float4 a0 = *(const float4*)(arow + j * 8);
        float4 a1 = *(const float4*)(arow + j * 8 + 4);
        float cjv = spg * bj[j];
        acc[0] = fmaf(a0.x, cjv, acc[0]); acc[1] = fmaf(a0.y, cjv, acc[1]);
        acc[2] = fmaf(a0.z, cjv, acc[2]); acc[3] = fmaf(a0.w, cjv, acc[3]);
        acc[4] = fmaf(a1.x, cjv, acc[4]); acc[5] = fmaf(a1.y, cjv, acc[5]);
        acc[6] = fmaf(a1.z, cjv, acc[6]); acc[7] = fmaf(a1.w, cjv, acc[7]);
    }
}

__global__ __launch_bounds__(256, 2)
void fused(const float* __restrict__ lamA, const float* __restrict__ lamB,
           const float* __restrict__ lamPi, const float* __restrict__ lamSP,
           const int* __restrict__ x, float* __restrict__ out,
           unsigned* __restrict__ sy, float* __restrict__ bmG,
           float* __restrict__ b3, float* __restrict__ e3)
{
    const int tid = threadIdx.x, w = tid >> 6, lane = tid & 63;
    const int n = lane >> 3, g = lane & 7;
    __shared__ __align__(16) float sAg[24 * kAS];   // A    [g][p][j][i]
    __shared__ __align__(16) float sLAg[24 * kAS];  // AlogA same layout
    __shared__ float sPi[192], sLPi[192], sSP[24], sLSP[24];
    __shared__ float bW[4][40 * kRS];               // per-subtree records
    __shared__ __half bMidH[13 * 64];               // mid beta, fp16
    __shared__ float sMs[13 * 8];                   // mid pre-norm sums
    __shared__ unsigned char xW[4][124];
    unsigned* trCnt = sy + 32;
    unsigned* trFlg = sy + 2080;

    // ---- init gate ----
    if (tid == 0) {
        if (blockIdx.x == 0) {
            for (int i = 0; i < 64; ++i) AGENT_ST(&trCnt[i * 32], 0u);
            __builtin_amdgcn_s_waitcnt(0);
            AGENT_ST(&sy[0], kMAGIC);
        }
        unsigned long sp = 0;
        while (AGENT_LD(&sy[0]) != kMAGIC) {
            if (++sp > (1UL << 24)) break;
            __builtin_amdgcn_s_sleep(2);
        }
    }
    __syncthreads();

    // ================= phase 0: parameters =================
    if (blockIdx.x == 0) {   // Bm softmax -> bmG (transposed [m][c][g]) + flag
        float* rr = &bW[0][0];
        int row = tid >> 2, part = tid & 3;
        int c = row >> 3, gg = row & 7, m0 = part * 32;
        float mx = -1e30f;
        for (int mm = 0; mm < 32; ++mm)
            mx = fmaxf(mx, lamB[(c * 128 + m0 + mm) * 8 + gg]);
        rr[tid] = mx;
        __syncthreads();
        float m4 = fmaxf(fmaxf(rr[row * 4], rr[row * 4 + 1]),
                         fmaxf(rr[row * 4 + 2], rr[row * 4 + 3]));
        float s = 0.f;
        for (int mm = 0; mm < 32; ++mm)
            s += expf(lamB[(c * 128 + m0 + mm) * 8 + gg] - m4);
        rr[256 + tid] = s;
        __syncthreads();
        float stot = rr[256 + row * 4] + rr[256 + row * 4 + 1]
                   + rr[256 + row * 4 + 2] + rr[256 + row * 4 + 3];
        float inv = 1.f / stot;
        for (int mm = 0; mm < 32; ++mm)
            AGENT_ST(&bmG[(m0 + mm) * 64 + c * 8 + gg],
                     expf(lamB[(c * 128 + m0 + mm) * 8 + gg] - m4) * inv);
        __syncthreads();
        if (tid == 0) AGENT_ST(&sy[4], kMAGIC2);
    }
    for (int col = tid; col < 192; col += 256) {   // A softmax over i -> g-major
        int j = col / 24; int rem = col - j * 24; int p = rem >> 3; int gg = rem & 7;
        float v[8]; float mx = -1e30f;
        #pragma unroll
        for (int i = 0; i < 8; ++i) {
            v[i] = lamA[((i * 8 + j) * 3 + p) * 8 + gg];
            mx = fmaxf(mx, v[i]);
        }
        float s = 0.f;
        #pragma unroll
        for (int i = 0; i < 8; ++i) { v[i] = expf(v[i] - mx); s += v[i]; }
        float inv = 1.f / s;
        int base = (gg * 3 + p) * kAS + j * 8;
        #pragma unroll
        for (int i = 0; i < 8; ++i) {
            float sm = v[i] * inv;
            sAg[base + i]  = sm;
            sLAg[base + i] = sm * logf(sm);
        }
    }
    for (int col = tid; col < 24; col += 256) {    // Pi softmax over c
        int p = col >> 3; int gg = col & 7;
        float v[8]; float mx = -1e30f;
        #pragma unroll
        for (int c = 0; c < 8; ++c) {
            v[c] = lamPi[(c * 3 + p) * 8 + gg];
            mx = fmaxf(mx, v[c]);
        }
        float s = 0.f;
        #pragma unroll
        for (int c = 0; c < 8; ++c) { v[c] = expf(v[c] - mx); s += v[c]; }
        float inv = 1.f / s;
        #pragma unroll
        for (int c = 0; c < 8; ++c) {
            int idx = (c * 3 + p) * 8 + gg;
            float sm = v[c] * inv;
            sPi[idx]  = sm;
            sLPi[idx] = logf(sm);
        }
    }
    if (tid < 8) {                                 // SP softmax over p
        int gg = tid;
        float v0 = lamSP[gg], v1 = lamSP[8 + gg], v2 = lamSP[16 + gg];
        float mx = fmaxf(v0, fmaxf(v1, v2));
        float e0 = expf(v0 - mx), e1 = expf(v1 - mx), e2 = expf(v2 - mx);
        float inv = 1.f / (e0 + e1 + e2);
        sSP[gg] = e0 * inv; sSP[8 + gg] = e1 * inv; sSP[16 + gg] = e2 * inv;
        sLSP[gg] = logf(e0 * inv); sLSP[8 + gg] = logf(e1 * inv); sLSP[16 + gg] = logf(e2 * inv);
    }
    if (tid == 0) {        // Bm gate: one fence per block per launch
        unsigned long sp = 0;
        while (AGENT_LD(&sy[4]) != kMAGIC2) {
            if (++sp > (1UL << 24)) break;
            __builtin_amdgcn_s_sleep(2);
        }
        __threadfence();
    }
    __syncthreads();

    const float* pBm = bmG;
    const int id = blockIdx.x * 4 + w, t = id / 27, q = id % 27, xb = t * kNPT;
    float* bw = &bW[w][0];
    unsigned char* xw = &xW[w][0];

    // ================= phase 1: subtree up-pass =================
    for (int u = lane; u < 121; u += 64) {
        int gx;
        if (u == 0)       gx = 13 + q;
        else if (u < 4)   gx = 40  + q * 3  + (u - 1);
        else if (u < 13)  gx = 121 + q * 9  + (u - 4);
        else if (u < 40)  gx = 364 + q * 27 + (u - 13);
        else              gx = 1093 + q * 81 + (u - 40);
        xw[u] = (unsigned char)x[xb + gx];
    }
    __builtin_amdgcn_wave_barrier();

    for (int e = 3; e >= 0; --e) {
        int cnt = P3[e];
        for (int base = 0; base < cnt; base += 8) {
            int node = base + n;
            if (node < cnt) {
                float acc[8];
                #pragma unroll
                for (int i = 0; i < 8; ++i) acc[i] = 0.f;
                #pragma unroll
                for (int k = 0; k < 3; ++k) {
                    float bj[8];
                    if (e == 3) {
                        leaf_beta(sPi, pBm, k, xw[40 + 3 * node + k], g, bj);
                    } else {
                        int co = (LO[e + 1] + 3 * node + k) * kRS + g;
                        #pragma unroll
                        for (int j = 0; j < 8; ++j) bj[j] = bw[co + j * 8];
                    }
                    matvec_acc(&sAg[(g * 3 + k) * kAS], bj, sSP[k * 8 + g], acc);
                }
                if (e == 0) {
                    #pragma unroll
                    for (int i = 0; i < 8; ++i) bw[i * 8 + g] = acc[i];  // raw tb root
                    int xv = xw[0];
                    float s = 0.f;
                    #pragma unroll
                    for (int i = 0; i < 8; ++i) { acc[i] *= pBm[xv * 64 + i * 8 + g]; s += acc[i]; }
                    float ig = __builtin_amdgcn_rcpf(s);
                    #pragma unroll
                    for (int i = 0; i < 8; ++i)
                        AGENT_ST(&b3[id * 64 + i * 8 + g], acc[i] * ig);
                } else {
                    int slot = LO[e] + node;
                    int xv = xw[slot];
                    float s = 0.f;
                    #pragma unroll
                    for (int i = 0; i < 8; ++i) { acc[i] *= pBm[xv * 64 + i * 8 + g]; s += acc[i]; }
                    float ig = __builtin_amdgcn_rcpf(s);
                    int bo = slot * kRS + g;
                    #pragma unroll
                    for (int i = 0; i < 8; ++i) bw[bo + i * 8] = acc[i] * ig;
                    bw[slot * kRS + 64 + g] = s;
                }
            }
        }
        __builtin_amdgcn_wave_barrier();
    }
    __builtin_amdgcn_s_waitcnt(0);
    if (lane == 0)
        __hip_atomic_fetch_add(&trCnt[t * 32], 1u, __ATOMIC_RELAXED,
                               __HIP_MEMORY_SCOPE_AGENT);

    // ================= phase 2: mid (levels 0-3), q==0 wave per tree =========
    if (q == 0) {
        unsigned long sp = 0;
        while (AGENT_LD(&trCnt[t * 32]) < 27u) {
            if (++sp > (1UL << 22)) break;
            __builtin_amdgcn_s_sleep(1);
        }
        __threadfence();   // one invalidate; b3 then read via cached loads
        float ellm = 0.f;
        for (int f = 2; f >= 0; --f) {
            int cnt = (f == 2) ? 9 : (f == 1 ? 3 : 1);
            int pl0 = (f == 2) ? 4 : (f == 1 ? 1 : 0);
            int cl0 = (f == 1) ? 4 : 1;
            for (int base = 0; base < cnt; base += 8) {
                int pi = base + n;
                if (pi < cnt) {
                    float acc[8];
                    #pragma unroll
                    for (int i = 0; i < 8; ++i) acc[i] = 0.f;
                    #pragma unroll
                    for (int k = 0; k < 3; ++k) {
                        float bj[8];
                        if (f == 2) {
                            const float* src = b3 + (t * 27 + 3 * pi + k) * 64 + g;
                            #pragma unroll
                            for (int j = 0; j < 8; ++j) bj[j] = src[j * 8];
                        } else {
                            int co = (cl0 + 3 * pi + k) * 64 + g;
                            #pragma unroll
                            for (int j = 0; j < 8; ++j)
                                bj[j] = __half2float(bMidH[co + j * 8]);
                        }
                        matvec_acc(&sAg[(g * 3 + k) * kAS], bj, sSP[k * 8 + g], acc);
                    }
                    int slot = pl0 + pi;
                    int xv = x[xb + slot];
                    float s = 0.f;
                    #pragma unroll
                    for (int i = 0; i < 8; ++i) { acc[i] *= pBm[xv * 64 + i * 8 + g]; s += acc[i]; }
                    float ig = __builtin_amdgcn_rcpf(s);
                    int bo = slot * 64 + g;
                    #pragma unroll
                    for (int i = 0; i < 8; ++i)
                        bMidH[bo + i * 8] = __float2half(acc[i] * ig);
                    sMs[slot * 8 + g] = s;
                }
            }
            __builtin_amdgcn_wave_barrier();
        }
        if (n == 0) {     // root: ell Bm term; slot0 := r = Bm/s
            int xv = x[xb];
            float invs = __builtin_amdgcn_rcpf(sMs[g]);
            #pragma unroll
            for (int c = 0; c < 8; ++c)
                ellm += __half2float(bMidH[c * 8 + g]) * pBm[xv * 64 + c * 8 + g];
            #pragma unroll
            for (int c = 0; c < 8; ++c)
                bMidH[c * 8 + g] = __float2half(pBm[xv * 64 + c * 8 + g] * invs);
        }
        __builtin_amdgcn_wave_barrier();
        for (int f = 1; f <= 3; ++f) {
            int cnt = (f == 1) ? 3 : (f == 2 ? 9 : 27);
            int cl0 = (f == 1) ? 1 : (f == 2 ? 4 : 13);
            int pl0 = (f == 1) ? 0 : (f == 2 ? 1 : 4);
            for (int base = 0; base < cnt; base += 8) {
                int ci = base + n;
                if (ci < cnt) {
                    int p = ci % 3;
                    int ps = (pl0 + ci / 3) * 64 + g;
                    float r[8];
                    #pragma unroll
                    for (int i = 0; i < 8; ++i) r[i] = __half2float(bMidH[ps + i * 8]);
                    float bj[8]; float sv = 0.f;
                    if (f == 3) {
                        const float* src = b3 + (t * 27 + ci) * 64 + g;
                        #pragma unroll
                        for (int j = 0; j < 8; ++j) bj[j] = src[j * 8];
                    } else {
                        int co = (cl0 + ci) * 64 + g;
                        #pragma unroll
                        for (int j = 0; j < 8; ++j) bj[j] = __half2float(bMidH[co + j * 8]);
                        sv = sMs[(cl0 + ci) * 8 + g];
                    }
                    float spg = sSP[p * 8 + g];
                    const float* arow = &sAg[(g * 3 + p) * kAS];
                    const float* lrow = &sLAg[(g * 3 + p) * kAS];
                    float esum = 0.f, lg = 0.f;
                    float ev[8];
                    #pragma unroll
                    for (int j = 0; j < 8; ++j) {
                        float4 a0 = *(const float4*)(arow + j * 8);
                        float4 a1 = *(const float4*)(arow + j * 8 + 4);
                        float4 l0 = *(const float4*)(lrow + j * 8);
                        float4 l1 = *(const float4*)(lrow + j * 8 + 4);
                        float s1 = r[0] * a0.x; s1 = fmaf(r[1], a0.y, s1);
                        s1 = fmaf(r[2], a0.z, s1); s1 = fmaf(r[3], a0.w, s1);
                        s1 = fmaf(r[4], a1.x, s1); s1 = fmaf(r[5], a1.y, s1);
                        s1 = fmaf(r[6], a1.z, s1); s1 = fmaf(r[7], a1.w, s1);
                        float s2 = r[0] * l0.x; s2 = fmaf(r[1], l0.y, s2);
                        s2 = fmaf(r[2], l0.z, s2); s2 = fmaf(r[3], l0.w, s2);
                        s2 = fmaf(r[4], l1.x, s2); s2 = fmaf(r[5], l1.y, s2);
                        s2 = fmaf(r[6], l1.z, s2); s2 = fmaf(r[7], l1.w, s2);
                        float bs = spg * bj[j];
                        ev[j] = bs * s1;
                        lg    = fmaf(bs, s2, lg);
                        esum += ev[j];
                    }
                    lg = fmaf(esum, sLSP[p * 8 + g], lg);
                    int xv = x[xb + cl0 + ci];
                    float Bmv[8];
                    #pragma unroll
                    for (int c = 0; c < 8; ++c) {
                        Bmv[c] = pBm[xv * 64 + c * 8 + g];
                        lg = fmaf(ev[c], Bmv[c], lg);
                    }
                    if (f == 3) {
                        #pragma unroll
                        for (int j = 0; j < 8; ++j)
                            AGENT_ST(&e3[(t * 27 + ci) * 64 + j * 8 + g], ev[j]);
                    } else {
                        int co = (cl0 + ci) * 64 + g;
                        #pragma unroll
                        for (int j = 0; j < 8; ++j)
                            bMidH[co + j * 8] = __float2half(
                                ev[j] * Bmv[j] * __builtin_amdgcn_rcpf(bj[j] * sv));
                    }
                    ellm += lg;
                }
            }
            __builtin_amdgcn_wave_barrier();
        }
        ellm += __shfl_xor(ellm, 8);
        ellm += __shfl_xor(ellm, 16);
        ellm += __shfl_xor(ellm, 32);
        if (n == 0) atomicAdd(&out[t * 8 + g], -ellm);
        __builtin_amdgcn_s_waitcnt(0);
        if (lane == 0) AGENT_ST(&trFlg[t * 32], kMAGIC2);
    }

    // ================= phase 3: subtree down-pass (p-class order) ============
    {
        unsigned long sp = 0;
        while (AGENT_LD(&trFlg[t * 32]) != kMAGIC2) {
            if (++sp > (1UL << 22)) break;
            __builtin_amdgcn_s_sleep(1);
        }
    }
    bw[lane] = AGENT_LD(&e3[id * 64 + lane]) * __builtin_amdgcn_rcpf(bw[lane]);
    __builtin_amdgcn_wave_barrier();

    float ell = 0.f;
    for (int e = 1; e <= 4; ++e) {
        int cnt = P3[e], pl0 = LO[e - 1];
        // e>=3: iterate one p-class at a time so p (and the A/ALA row base)
        // is wave-uniform -> conflict-free broadcast b128 reads.
        int nclass  = (e >= 3) ? 3 : 1;
        int m       = (e >= 3) ? cnt / 3 : cnt;
        for (int p0 = 0; p0 < nclass; ++p0) {
            for (int base = 0; base < m; base += 8) {
                int idx = base + n;
                if (idx < m) {
                    int ci = (e >= 3) ? (p0 + 3 * idx) : idx;
                    int p  = (e >= 3) ? p0 : (ci % 3);
                    int ps = (pl0 + ci / 3) * kRS + g;
                    float r[8];
                    #pragma unroll
                    for (int i = 0; i < 8; ++i) r[i] = bw[ps + i * 8];
                    float bj[8]; float sv = 0.f;
                    int xv;
                    int co = 0;
                    if (e == 4) {
                        xv = xw[40 + ci];
                        leaf_beta(sPi, pBm, p, xv, g, bj);
                    } else {
                        int slot = LO[e] + ci;
                        xv = xw[slot];
                        co = slot * kRS + g;
                        #pragma unroll
                        for (int j = 0; j < 8; ++j) bj[j] = bw[co + j * 8];
                        sv = bw[slot * kRS + 64 + g];
                    }
                    float spg = sSP[p * 8 + g];
                    const float* arow = &sAg[(g * 3 + p) * kAS];
                    const float* lrow = &sLAg[(g * 3 + p) * kAS];
                    float esum = 0.f, lg = 0.f;
                    float ev[8];
                    #pragma unroll
                    for (int j = 0; j < 8; ++j) {
                        float4 a0 = *(const float4*)(arow + j * 8);
                        float4 a1 = *(const float4*)(arow + j * 8 + 4);
                        float4 l0 = *(const float4*)(lrow + j * 8);
                        float4 l1 = *(const float4*)(lrow + j * 8 + 4);
                        float s1 = r[0] * a0.x; s1 = fmaf(r[1], a0.y, s1);
                        s1 = fmaf(r[2], a0.z, s1); s1 = fmaf(r[3], a0.w, s1);
                        s1 = fmaf(r[4], a1.x, s1); s1 = fmaf(r[5], a1.y, s1);
                        s1 = fmaf(r[6], a1.z, s1); s1 = fmaf(r[7], a1.w, s1);
                        float s2 = r[0] * l0.x; s2 = fmaf(r[1], l0.y, s2);
                        s2 = fmaf(r[2], l0.z, s2); s2 = fmaf(r[3], l0.w, s2);
                        s2 = fmaf(r[4], l1.x, s2); s2 = fmaf(r[5], l1.y, s2);
                        s2 = fmaf(r[6], l1.z, s2); s2 = fmaf(r[7], l1.w, s2);
                        float bs = spg * bj[j];
                        ev[j] = bs * s1;
                        lg    = fmaf(bs, s2, lg);
                        esum += ev[j];
                    }
                    lg = fmaf(esum, sLSP[p * 8 + g], lg);
                    float Bmv[8];
                    #pragma unroll
                    for (int c = 0; c < 8; ++c) {
                        Bmv[c] = pBm[xv * 64 + c * 8 + g];
                        lg = fmaf(ev[c], Bmv[c], lg);
                    }
                    if (e < 4) {
                        #pragma unroll
                        for (int j = 0; j < 8; ++j)
                            bw[co + j * 8] = ev[j] * Bmv[j]
                                * __builtin_amdgcn_rcpf(bj[j] * sv);
                    } else {
                        #pragma unroll
                        for (int c = 0; c < 8; ++c)
                            lg = fmaf(ev[c], sLPi[(c * 3 + p) * 8 + g], lg);
                    }
                    ell += lg;
                }
            }
        }
        __builtin_amdgcn_wave_barrier();
    }

    ell += __shfl_xor(ell, 8);
    ell += __shfl_xor(ell, 16);
    ell += __shfl_xor(ell, 32);
    if (n == 0) atomicAdd(&out[t * 8 + g], -ell);
}

} // namespace

extern "C" void kernel_launch(void* const* d_in, const int* in_sizes, int n_in,
                              void* d_out, int out_size, void* d_ws, size_t ws_size,
                              hipStream_t stream) {
    const float* lamA  = (const float*)d_in[0];
    const float* lamB  = (const float*)d_in[1];
    const float* lamPi = (const float*)d_in[2];
    const float* lamSP = (const float*)d_in[3];
    const int*   x     = (const int*)d_in[4];
    float* out = (float*)d_out;
    unsigned* sy  = (unsigned*)d_ws;        // sync area (32 KB)
    float* bmG = (float*)d_ws + 8192;       // 8192 floats
    float* b3  = bmG + 8192;                // 1728*64
    float* e3  = b3 + 1728 * 64;            // 1728*64

    fused<<<dim3(432), dim3(256), 0, stream>>>(
        lamA, lamB, lamPi, lamSP, x, out, sy, bmG, b3, e3);
}